// Round 10
// baseline (41.517 us; speedup 1.0000x reference)
//
#include <hip/hip_runtime.h>
#include <hip/hip_fp16.h>

typedef _Float16 f16;

// ---------------- one-time LUT build: g_ty(x) on a uniform grid ----------------
// 8 ROWS PER BLOCK (128 threads), blockIdx.y = type. Weight columns hoisted to
// registers and amortized over the 8 rows; layers chained via LDS + barriers.
__global__ __launch_bounds__(128)
void build_table(const float* __restrict__ w00, const float* __restrict__ b00,
                 const float* __restrict__ w01, const float* __restrict__ b01,
                 const float* __restrict__ w02, const float* __restrict__ b02,
                 const float* __restrict__ w10, const float* __restrict__ b10,
                 const float* __restrict__ w11, const float* __restrict__ b11,
                 const float* __restrict__ w12, const float* __restrict__ b12,
                 f16* __restrict__ tab, int rowsPerType, float xmin, float h)
{
    __shared__ float h0s[8][24];
    __shared__ float h1s[8][48];

    const int ty  = blockIdx.y;
    const int r0  = blockIdx.x * 8;
    const int tid = threadIdx.x;

    const float* __restrict__ W0 = ty ? w10 : w00;
    const float* __restrict__ B0 = ty ? b10 : b00;
    const float* __restrict__ W1 = ty ? w11 : w01;
    const float* __restrict__ B1 = ty ? b11 : b01;
    const float* __restrict__ W2 = ty ? w12 : w02;
    const float* __restrict__ B2 = ty ? b12 : b02;

    // phase 1: h0[q][j] for 8 rows x 24 units
#pragma unroll
    for (int p = 0; p < 2; ++p) {
        const int idx = p * 128 + tid;
        if (idx < 192) {
            const int q = idx / 24, j = idx - q * 24;
            const float x = __builtin_fmaf((float)(r0 + q), h, xmin);
            h0s[q][j] = tanhf(__builtin_fmaf(x, W0[j], B0[j]));
        }
    }
    __syncthreads();

    // phase 2: h1[q][k]; thread = (half, k), W1 column in registers, 4 rows each
    if (tid < 96) {
        const int half = tid / 48, k = tid - half * 48;
        float w1c[24];
#pragma unroll
        for (int j = 0; j < 24; ++j) w1c[j] = W1[j * 48 + k];
        const float bk = B1[k];
        const int km = (k < 24) ? k : (k - 24);
#pragma unroll
        for (int qq = 0; qq < 4; ++qq) {
            const int q = half * 4 + qq;
            float a = bk;
#pragma unroll
            for (int j = 0; j < 24; ++j)
                a = __builtin_fmaf(h0s[q][j], w1c[j], a);
            h1s[q][k] = tanhf(a) + h0s[q][km];
        }
    }
    __syncthreads();

    // phase 3: g[q][e]; thread = e, W2 column in registers, loops 8 rows
    if (tid < 96) {
        const int e = tid;
        float w2c[48];
#pragma unroll
        for (int k = 0; k < 48; ++k) w2c[k] = W2[k * 96 + e];
        const float be = B2[e];
        const int em = (e < 48) ? e : (e - 48);
#pragma unroll
        for (int q = 0; q < 8; ++q) {
            if (r0 + q < rowsPerType) {
                float a = be;
#pragma unroll
                for (int k = 0; k < 48; ++k)
                    a = __builtin_fmaf(h1s[q][k], w2c[k], a);
                tab[((size_t)ty * rowsPerType + r0 + q) * 96 + e] = (f16)(tanhf(a) + h1s[q][em]);
            }
        }
    }
}

// ---------------- main: 2 ATOMS PER BLOCK, packed-f16 lerp, fused contraction ----------------
// rows r: 0..45 type0 (s=r), 46/47 pad; 48..139 type1 (s=r-2), 140..143 pad.
// 9 row-tiles of 16; wave w (of 3) owns tiles {w, w+3, w+6} for BOTH atoms.
__global__ __launch_bounds__(192, 4)
void emb_main(const float* __restrict__ dmat, const f16* __restrict__ tab,
              int nseg, float scale, float offs,
              float* __restrict__ out)
{
    __shared__ float DD[2][144 * 4];     // [atom][r][4] f32, pads zero
    __shared__ float Y2s[2][3 * 4 * 96]; // [atom][wave][d][e] partials

    const int tid = threadIdx.x;
    const int w = tid >> 6, lane = tid & 63;
    const int l15 = lane & 15, lhi = lane >> 4;
    const int nA = blockIdx.x * 2, nB = nA + 1;

    // DD fill: wave w fills the 48 rows of its own 3 tiles, both atoms
    if (lane < 48) {
        const int t = w + 3 * (lane >> 4);
        const int r = t * 16 + (lane & 15);
        const bool t0 = (t < 3);
        const int  s  = t0 ? r : (r - 2);
        const bool ok = t0 ? (r < 46) : (r < 140);
        float4 vA = make_float4(0.f, 0.f, 0.f, 0.f);
        float4 vB = make_float4(0.f, 0.f, 0.f, 0.f);
        if (ok) {
            vA = *reinterpret_cast<const float4*>(dmat + (size_t)nA * 552 + s * 4);
            vB = *reinterpret_cast<const float4*>(dmat + (size_t)nB * 552 + s * 4);
        }
        *reinterpret_cast<float4*>(&DD[0][r * 4]) = vA;
        *reinterpret_cast<float4*>(&DD[1][r * 4]) = vB;
    }

    float ypA[24], ypB[24];
#pragma unroll
    for (int i = 0; i < 24; ++i) { ypA[i] = 0.f; ypB[i] = 0.f; }

    const float clampHi = (float)nseg - 0.5f;
    const int rowU32 = 48;

#pragma unroll
    for (int it = 0; it < 3; ++it) {
        const int t = w + 3 * it;
        const int tyt = (t >= 3);
        const uint32_t* __restrict__ tb =
            reinterpret_cast<const uint32_t*>(tab + (size_t)tyt * (nseg + 1) * 96);

        int irowA[4], irowB[4];
        __half2 frA[4], frB[4];
        float4 ddA[4], ddB[4];
#pragma unroll
        for (int rg = 0; rg < 4; ++rg) {
            const int r = t * 16 + lhi * 4 + rg;
            {
                const float x = DD[0][r * 4];
                float u = __builtin_fmaf(x, scale, offs);
                u = fminf(fmaxf(u, 0.f), clampHi);
                const int i = (int)u;
                irowA[rg] = i * rowU32;
                const float fr = u - (float)i;
                frA[rg] = __float2half2_rn(fr);
                ddA[rg] = *reinterpret_cast<const float4*>(&DD[0][r * 4]);
            }
            {
                const float x = DD[1][r * 4];
                float u = __builtin_fmaf(x, scale, offs);
                u = fminf(fmaxf(u, 0.f), clampHi);
                const int i = (int)u;
                irowB[rg] = i * rowU32;
                const float fr = u - (float)i;
                frB[rg] = __float2half2_rn(fr);
                ddB[rg] = *reinterpret_cast<const float4*>(&DD[1][r * 4]);
            }
        }

#pragma unroll
        for (int c = 0; c < 3; ++c) {
            const int b = c * 8;
#pragma unroll
            for (int rg = 0; rg < 4; ++rg) {
                // atom A
                {
                    const uint32_t* p = tb + irowA[rg] + c * 16 + l15;
                    const uint32_t alo = p[0];
                    const uint32_t ahi = p[rowU32];
                    const __half2 lo2 = *reinterpret_cast<const __half2*>(&alo);
                    const __half2 hi2 = *reinterpret_cast<const __half2*>(&ahi);
                    const __half2 g2 = __hfma2(frA[rg], __hsub2(hi2, lo2), lo2);
                    const float g0 = __low2float(g2);
                    const float g1 = __high2float(g2);
                    ypA[b + 0] = __builtin_fmaf(ddA[rg].x, g0, ypA[b + 0]);
                    ypA[b + 1] = __builtin_fmaf(ddA[rg].y, g0, ypA[b + 1]);
                    ypA[b + 2] = __builtin_fmaf(ddA[rg].z, g0, ypA[b + 2]);
                    ypA[b + 3] = __builtin_fmaf(ddA[rg].w, g0, ypA[b + 3]);
                    ypA[b + 4] = __builtin_fmaf(ddA[rg].x, g1, ypA[b + 4]);
                    ypA[b + 5] = __builtin_fmaf(ddA[rg].y, g1, ypA[b + 5]);
                    ypA[b + 6] = __builtin_fmaf(ddA[rg].z, g1, ypA[b + 6]);
                    ypA[b + 7] = __builtin_fmaf(ddA[rg].w, g1, ypA[b + 7]);
                }
                // atom B (independent chain -> ILP)
                {
                    const uint32_t* p = tb + irowB[rg] + c * 16 + l15;
                    const uint32_t alo = p[0];
                    const uint32_t ahi = p[rowU32];
                    const __half2 lo2 = *reinterpret_cast<const __half2*>(&alo);
                    const __half2 hi2 = *reinterpret_cast<const __half2*>(&ahi);
                    const __half2 g2 = __hfma2(frB[rg], __hsub2(hi2, lo2), lo2);
                    const float g0 = __low2float(g2);
                    const float g1 = __high2float(g2);
                    ypB[b + 0] = __builtin_fmaf(ddB[rg].x, g0, ypB[b + 0]);
                    ypB[b + 1] = __builtin_fmaf(ddB[rg].y, g0, ypB[b + 1]);
                    ypB[b + 2] = __builtin_fmaf(ddB[rg].z, g0, ypB[b + 2]);
                    ypB[b + 3] = __builtin_fmaf(ddB[rg].w, g0, ypB[b + 3]);
                    ypB[b + 4] = __builtin_fmaf(ddB[rg].x, g1, ypB[b + 4]);
                    ypB[b + 5] = __builtin_fmaf(ddB[rg].y, g1, ypB[b + 5]);
                    ypB[b + 6] = __builtin_fmaf(ddB[rg].z, g1, ypB[b + 6]);
                    ypB[b + 7] = __builtin_fmaf(ddB[rg].w, g1, ypB[b + 7]);
                }
            }
        }
    }

    // reduce over the 4 lhi row-groups
#pragma unroll
    for (int i = 0; i < 24; ++i) {
        float vA = ypA[i];
        vA += __shfl_xor(vA, 16);
        vA += __shfl_xor(vA, 32);
        ypA[i] = vA;
        float vB = ypB[i];
        vB += __shfl_xor(vB, 16);
        vB += __shfl_xor(vB, 32);
        ypB[i] = vB;
    }
    if (lhi == 0) {
#pragma unroll
        for (int c = 0; c < 3; ++c)
#pragma unroll
            for (int d = 0; d < 4; ++d) {
                *reinterpret_cast<float2*>(&Y2s[0][w * 384 + d * 96 + c * 32 + 2 * l15]) =
                    make_float2(ypA[c * 8 + d], ypA[c * 8 + 4 + d]);
                *reinterpret_cast<float2*>(&Y2s[1][w * 384 + d * 96 + c * 32 + 2 * l15]) =
                    make_float2(ypB[c * 8 + d], ypB[c * 8 + 4 + d]);
            }
    }
    __syncthreads();

    // stage 4: all 192 lanes active: lanes 0..95 atom A, 96..191 atom B
    {
        const int at = tid / 96;
        const int e  = tid - at * 96;
        const float* Y = Y2s[at];
        constexpr float inv = 1.0f / 138.0f;
        const float x0 = (Y[e]       + Y[384 + e]       + Y[768 + e])       * inv;
        const float x1 = (Y[96 + e]  + Y[384 + 96 + e]  + Y[768 + 96 + e])  * inv;
        const float x2 = (Y[192 + e] + Y[384 + 192 + e] + Y[768 + 192 + e]) * inv;
        const float x3 = (Y[288 + e] + Y[384 + 288 + e] + Y[768 + 288 + e]) * inv;
        float rv[8];
#pragma unroll
        for (int k = 0; k < 8; ++k) {
            const float k0 = (Y[k]       + Y[384 + k]       + Y[768 + k])       * inv;
            const float k1 = (Y[96 + k]  + Y[384 + 96 + k]  + Y[768 + 96 + k])  * inv;
            const float k2 = (Y[192 + k] + Y[384 + 192 + k] + Y[768 + 192 + k]) * inv;
            const float k3 = (Y[288 + k] + Y[384 + 288 + k] + Y[768 + 288 + k]) * inv;
            float rr = x0 * k0;
            rr = __builtin_fmaf(x1, k1, rr);
            rr = __builtin_fmaf(x2, k2, rr);
            rr = __builtin_fmaf(x3, k3, rr);
            rv[k] = rr;
        }
        float* op = out + (size_t)(nA + at) * 768 + e * 8;
        *reinterpret_cast<float4*>(op)     = make_float4(rv[0], rv[1], rv[2], rv[3]);
        *reinterpret_cast<float4*>(op + 4) = make_float4(rv[4], rv[5], rv[6], rv[7]);
    }
}

extern "C" void kernel_launch(void* const* d_in, const int* in_sizes, int n_in,
                              void* d_out, int out_size, void* d_ws, size_t ws_size,
                              hipStream_t stream)
{
    const float* dmat = (const float*)d_in[0];
    const int n_atoms = in_sizes[0] / 552;   // 6144 (even)

    int nseg = 1024;
    while ((size_t)2 * (size_t)(nseg + 1) * 96 * sizeof(f16) > ws_size && nseg > 16)
        nseg >>= 1;
    const float xmin = -8.f, xmax = 8.f;
    const float h     = (xmax - xmin) / (float)nseg;
    const float scale = (float)nseg / (xmax - xmin);
    const float offs  = -xmin * scale;
    f16* tab = (f16*)d_ws;

    const int rowsPerType = nseg + 1;
    dim3 bgrid((rowsPerType + 7) / 8, 2);
    build_table<<<bgrid, 128, 0, stream>>>(
        (const float*)d_in[1],  (const float*)d_in[2],
        (const float*)d_in[3],  (const float*)d_in[4],
        (const float*)d_in[5],  (const float*)d_in[6],
        (const float*)d_in[7],  (const float*)d_in[8],
        (const float*)d_in[9],  (const float*)d_in[10],
        (const float*)d_in[11], (const float*)d_in[12],
        tab, rowsPerType, xmin, h);

    emb_main<<<n_atoms / 2, 192, 0, stream>>>(dmat, tab, nseg, scale, offs, (float*)d_out);
}